// Round 7
// baseline (1644.437 us; speedup 1.0000x reference)
//
#include <hip/hip_runtime.h>
#include <stdint.h>

#define Hh   51
#define Bsz  1024
#define Tin  512
#define Ttot 576      // Tin + future(64)
#define NB   4        // batch elements per block
#define BLK  1024     // 16 waves; grid 256 = 1 block/CU, whole batch resident

typedef float v2f __attribute__((ext_vector_type(2)));

__device__ __forceinline__ float fast_sigmoid(float x) {
    return 1.0f / (1.0f + __expf(-x));
}
__device__ __forceinline__ v2f pk_fma(v2f a, v2f b, v2f c) {
#if __has_builtin(__builtin_elementwise_fma)
    return __builtin_elementwise_fma(a, b, c);   // -> v_pk_fma_f32
#else
    v2f r; r.x = __builtin_fmaf(a.x, b.x, c.x); r.y = __builtin_fmaf(a.y, b.y, c.y);
    return r;
#endif
}

// tid = jj*16 + G*4 + qq : quarter-row split. 48 pinned weight floats/thread
// fits the 128-reg budget (4 waves/EU) WITHOUT spill -> 16 waves/CU, 2x R6.
// LDS h layout: padded word w (0..127: [h1(51)|0|h2@64(51)|0]) stored in
// stride-36 quarters: addr = (w>>5)*36 + (w&31). Each read instruction's 4
// qq-addresses then hit 4 distinct bank quartets (no 4-way conflicts).
__global__ __launch_bounds__(BLK, 4)
void lstm_seq_kernel(const float* __restrict__ inp,    // [B, Tin]
                     const float* __restrict__ Wih1,   // [204, 1]
                     const float* __restrict__ Whh1,   // [204, 51]
                     const float* __restrict__ bih1,   // [204]
                     const float* __restrict__ bhh1,   // [204]
                     const float* __restrict__ Wih2,   // [204, 51]
                     const float* __restrict__ Whh2,   // [204, 51]
                     const float* __restrict__ bih2,   // [204]
                     const float* __restrict__ bhh2,   // [204]
                     const float* __restrict__ Wl,     // [1, 51]
                     const float* __restrict__ blp,    // [1]
                     float* __restrict__ outp)         // [B, Ttot]
{
    const int tid = threadIdx.x;
    const int jj  = tid >> 4;            // hidden unit 0..63 (51 active)
    const int G   = (tid >> 2) & 3;      // gate: 0=i 1=f 2=g 3=o
    const int qq  = tid & 3;             // quarter of the row
    const int jc  = (jj < Hh) ? jj : (Hh - 1);
    const int row = G * Hh + jc;         // PyTorch gate-row
    const int b0  = blockIdx.x * NB;
    const int wv  = tid >> 6, ln = tid & 63;
    const int bl  = ((qq & 1) << 1) | (qq >> 1);  // batch this lane owns post-combine

    __shared__ float hsm[2][NB][144];    // parity double-buffered quartered h
    __shared__ float xout[4];            // fed-back outputs (future phase)

    for (int k = tid; k < 2 * NB * 144; k += BLK) ((float*)hsm)[k] = 0.f;
    if (tid < 4) xout[tid] = 0.f;

    // ---- quarter-row weights: 8 + 16 v2f = 48 floats, pinned ----
    v2f w1q[8];                          // padded-64 Whh1 row, words qq*16..+15
#pragma unroll
    for (int p = 0; p < 8; ++p) {
        int e0 = qq * 16 + 2 * p, e1 = e0 + 1;
        w1q[p].x = (e0 < Hh) ? Whh1[row * Hh + e0] : 0.f;
        w1q[p].y = (e1 < Hh) ? Whh1[row * Hh + e1] : 0.f;
    }
    v2f w2q[16];                         // padded-128 [Wih2|0|Whh2|0], words qq*32..+31
#pragma unroll
    for (int p = 0; p < 16; ++p) {
        int k0 = qq * 32 + 2 * p, k1 = k0 + 1;
        float a = (k0 < Hh) ? Wih2[row * Hh + k0]
                : ((k0 >= 64 && k0 < 64 + Hh) ? Whh2[row * Hh + k0 - 64] : 0.f);
        float b = (k1 < Hh) ? Wih2[row * Hh + k1]
                : ((k1 >= 64 && k1 < 64 + Hh) ? Whh2[row * Hh + k1 - 64] : 0.f);
        w2q[p].x = a; w2q[p].y = b;
    }
#pragma unroll
    for (int p = 0; p < 8; ++p)  asm volatile("" : "+v"(w1q[p]));
#pragma unroll
    for (int p = 0; p < 16; ++p) asm volatile("" : "+v"(w2q[p]));

    const float b1r = bih1[row] + bhh1[row];
    const float wi1 = Wih1[row];
    const float b2r = bih2[row] + bhh2[row];
    const float wlv = (ln < Hh) ? Wl[ln] : 0.f;   // used by waves 0..3
    const float blv = blp[0];
    const bool  tg  = (G == 2);
    const float tgm = tg ? 2.f : 1.f;
    const float tgo = tg ? -1.f : 0.f;
    const bool  st_lane = (G == 0) && (jj < Hh);
    float c1 = 0.f, c2 = 0.f;

    float xa0 = inp[(size_t)(b0 + 0) * Tin];
    float xa1 = inp[(size_t)(b0 + 1) * Tin];
    float xa2 = inp[(size_t)(b0 + 2) * Tin];
    float xa3 = inp[(size_t)(b0 + 3) * Tin];

    __syncthreads();

    for (int t = 0; t < Ttot; ++t) {
        const int p0 = t & 1, p1 = p0 ^ 1;

        // ---- front: waves 0..3 compute step t-1's output from stable h2 ----
        if (wv < 4 && t > 0) {
            int a = (ln < 32) ? (72 + ln) : (76 + ln);   // qaddr(64+ln)
            float h2v = hsm[p0][wv][a];                  // 0 for ln>=51 (pad)
            float cb = wlv * h2v;
#pragma unroll
            for (int m = 32; m >= 1; m >>= 1) cb += __shfl_xor(cb, m, 64);
            if (ln == 0) {
                float o = cb + blv;
                xout[wv] = o;
                outp[(size_t)(b0 + wv) * Ttot + (t - 1)] = o;
            }
        }
        if (t >= Tin) __syncthreads();   // future phase: x depends on xout

        float x0, x1, x2, x3;
        if (t < Tin) { x0 = xa0; x1 = xa1; x2 = xa2; x3 = xa3; }
        else         { x0 = xout[0]; x1 = xout[1]; x2 = xout[2]; x3 = xout[3]; }
        float xn0 = 0.f, xn1 = 0.f, xn2 = 0.f, xn3 = 0.f;
        if (t + 1 < Tin) {
            xn0 = inp[(size_t)(b0 + 0) * Tin + t + 1];
            xn1 = inp[(size_t)(b0 + 1) * Tin + t + 1];
            xn2 = inp[(size_t)(b0 + 2) * Tin + t + 1];
            xn3 = inp[(size_t)(b0 + 3) * Tin + t + 1];
        }

        // ================= P1: layer-1 gates (quarter dots) =================
        float s;
        {
            v2f aA0 = {(qq == 0) ? __builtin_fmaf(x0, wi1, b1r) : 0.f, 0.f}, aA1 = {0.f, 0.f};
            v2f aB0 = {(qq == 0) ? __builtin_fmaf(x1, wi1, b1r) : 0.f, 0.f}, aB1 = {0.f, 0.f};
            v2f aC0 = {(qq == 0) ? __builtin_fmaf(x2, wi1, b1r) : 0.f, 0.f}, aC1 = {0.f, 0.f};
            v2f aD0 = {(qq == 0) ? __builtin_fmaf(x3, wi1, b1r) : 0.f, 0.f}, aD1 = {0.f, 0.f};
            const int base1 = (qq >> 1) * 36 + (qq & 1) * 16;  // quartered addr
            const float4* hA = (const float4*)&hsm[p1][0][base1];
            const float4* hB = (const float4*)&hsm[p1][1][base1];
            const float4* hC = (const float4*)&hsm[p1][2][base1];
            const float4* hD = (const float4*)&hsm[p1][3][base1];
#pragma unroll
            for (int p = 0; p < 4; ++p) {
                float4 a4 = hA[p], b4 = hB[p], c4 = hC[p], d4 = hD[p];
                aA0 = pk_fma(w1q[2 * p],     (v2f){a4.x, a4.y}, aA0);
                aA1 = pk_fma(w1q[2 * p + 1], (v2f){a4.z, a4.w}, aA1);
                aB0 = pk_fma(w1q[2 * p],     (v2f){b4.x, b4.y}, aB0);
                aB1 = pk_fma(w1q[2 * p + 1], (v2f){b4.z, b4.w}, aB1);
                aC0 = pk_fma(w1q[2 * p],     (v2f){c4.x, c4.y}, aC0);
                aC1 = pk_fma(w1q[2 * p + 1], (v2f){c4.z, c4.w}, aC1);
                aD0 = pk_fma(w1q[2 * p],     (v2f){d4.x, d4.y}, aD0);
                aD1 = pk_fma(w1q[2 * p + 1], (v2f){d4.z, d4.w}, aD1);
            }
            float pA = (aA0.x + aA1.x) + (aA0.y + aA1.y);
            float pB = (aB0.x + aB1.x) + (aB0.y + aB1.y);
            float pC = (aC0.x + aC1.x) + (aC0.y + aC1.y);
            float pD = (aD0.x + aD1.x) + (aD0.y + aD1.y);
            // reduce-scatter: 4 swizzles; lane qq ends with batch bl's pre-act
            float t1 = (qq & 1) ? pA : pC;  float r1 = __shfl_xor(t1, 1, 64);
            float t2 = (qq & 1) ? pB : pD;  float r2 = __shfl_xor(t2, 1, 64);
            float uu = ((qq & 1) ? pC : pA) + r1;
            float vv = ((qq & 1) ? pD : pB) + r2;
            float t3 = (qq & 2) ? uu : vv;  float r3 = __shfl_xor(t3, 2, 64);
            float pre = ((qq & 2) ? vv : uu) + r3;
            s = __builtin_fmaf(fast_sigmoid(pre * tgm), tgm, tgo);
        }
        {   // gate gather within the 16-lane unit group (same qq => same batch)
            float f_ = __shfl_xor(s, 4, 64);
            float g_ = __shfl_xor(s, 8, 64);
            float o_ = __shfl_xor(f_, 8, 64);
            if (st_lane) {
                c1 = __builtin_fmaf(f_, c1, s * g_);
                float th = 2.f * fast_sigmoid(2.f * c1) - 1.f;
                hsm[p0][bl][(jj < 32) ? jj : (jj + 4)] = o_ * th;   // h1_t
            }
        }
        __syncthreads();

        // ============ P2: layer-2 gates (quarter dots over [h1;h2]) =========
        {
            v2f aA0 = {(qq == 0) ? b2r : 0.f, 0.f}, aA1 = {0.f, 0.f};
            v2f aB0 = {(qq == 0) ? b2r : 0.f, 0.f}, aB1 = {0.f, 0.f};
            v2f aC0 = {(qq == 0) ? b2r : 0.f, 0.f}, aC1 = {0.f, 0.f};
            v2f aD0 = {(qq == 0) ? b2r : 0.f, 0.f}, aD1 = {0.f, 0.f};
            const int base2 = qq * 36;
            const float4* hA = (const float4*)&hsm[p0][0][base2];
            const float4* hB = (const float4*)&hsm[p0][1][base2];
            const float4* hC = (const float4*)&hsm[p0][2][base2];
            const float4* hD = (const float4*)&hsm[p0][3][base2];
#pragma unroll
            for (int p = 0; p < 8; ++p) {
                float4 a4 = hA[p], b4 = hB[p], c4 = hC[p], d4 = hD[p];
                aA0 = pk_fma(w2q[2 * p],     (v2f){a4.x, a4.y}, aA0);
                aA1 = pk_fma(w2q[2 * p + 1], (v2f){a4.z, a4.w}, aA1);
                aB0 = pk_fma(w2q[2 * p],     (v2f){b4.x, b4.y}, aB0);
                aB1 = pk_fma(w2q[2 * p + 1], (v2f){b4.z, b4.w}, aB1);
                aC0 = pk_fma(w2q[2 * p],     (v2f){c4.x, c4.y}, aC0);
                aC1 = pk_fma(w2q[2 * p + 1], (v2f){c4.z, c4.w}, aC1);
                aD0 = pk_fma(w2q[2 * p],     (v2f){d4.x, d4.y}, aD0);
                aD1 = pk_fma(w2q[2 * p + 1], (v2f){d4.z, d4.w}, aD1);
            }
            float pA = (aA0.x + aA1.x) + (aA0.y + aA1.y);
            float pB = (aB0.x + aB1.x) + (aB0.y + aB1.y);
            float pC = (aC0.x + aC1.x) + (aC0.y + aC1.y);
            float pD = (aD0.x + aD1.x) + (aD0.y + aD1.y);
            float t1 = (qq & 1) ? pA : pC;  float r1 = __shfl_xor(t1, 1, 64);
            float t2 = (qq & 1) ? pB : pD;  float r2 = __shfl_xor(t2, 1, 64);
            float uu = ((qq & 1) ? pC : pA) + r1;
            float vv = ((qq & 1) ? pD : pB) + r2;
            float t3 = (qq & 2) ? uu : vv;  float r3 = __shfl_xor(t3, 2, 64);
            float pre = ((qq & 2) ? vv : uu) + r3;
            s = __builtin_fmaf(fast_sigmoid(pre * tgm), tgm, tgo);
        }
        {
            float f_ = __shfl_xor(s, 4, 64);
            float g_ = __shfl_xor(s, 8, 64);
            float o_ = __shfl_xor(f_, 8, 64);
            if (st_lane) {
                c2 = __builtin_fmaf(f_, c2, s * g_);
                float th = 2.f * fast_sigmoid(2.f * c2) - 1.f;
                // h2_t -> buf p1 (= next step's p0), quartered addr of word 64+jj
                hsm[p1][bl][(jj < 32) ? (72 + jj) : (76 + jj)] = o_ * th;
            }
        }
        __syncthreads();
        xa0 = xn0; xa1 = xn1; xa2 = xn2; xa3 = xn3;
    }

    // ---- final output (t = Ttot-1): h2 sits in buf[Ttot&1] ----
    if (wv < 4) {
        int a = (ln < 32) ? (72 + ln) : (76 + ln);
        float h2v = hsm[Ttot & 1][wv][a];
        float cb = wlv * h2v;
#pragma unroll
        for (int m = 32; m >= 1; m >>= 1) cb += __shfl_xor(cb, m, 64);
        if (ln == 0) outp[(size_t)(b0 + wv) * Ttot + (Ttot - 1)] = cb + blv;
    }
}

extern "C" void kernel_launch(void* const* d_in, const int* in_sizes, int n_in,
                              void* d_out, int out_size, void* d_ws, size_t ws_size,
                              hipStream_t stream) {
    (void)in_sizes; (void)n_in; (void)out_size; (void)d_ws; (void)ws_size;
    lstm_seq_kernel<<<dim3(Bsz / NB), dim3(BLK), 0, stream>>>(
        (const float*)d_in[0], (const float*)d_in[1],
        (const float*)d_in[2], (const float*)d_in[3],
        (const float*)d_in[4], (const float*)d_in[5],
        (const float*)d_in[6], (const float*)d_in[7],
        (const float*)d_in[8], (const float*)d_in[9],
        (const float*)d_in[10], (float*)d_out);
}

// Round 8
// 1388.946 us; speedup vs baseline: 1.1839x; 1.1839x over previous
//
#include <hip/hip_runtime.h>
#include <stdint.h>

#define Hh   51
#define Bsz  1024
#define Tin  512
#define Ttot 576      // Tin + future(64)
#define NBB  16       // batches per block (MFMA N dimension)
#define BLK  832      // 13 waves = 13 M-tiles of 16 rows (208 >= 204 gate rows)

typedef __attribute__((ext_vector_type(8))) short short8;   // 8 x bf16 frag
typedef __attribute__((ext_vector_type(4))) float f32x4;    // C/D frag

__device__ __forceinline__ float fast_sigmoid(float x){ return 1.f/(1.f+__expf(-x)); }
__device__ __forceinline__ uint16_t f2bf(float f){
    union{float f;uint32_t u;} v; v.f=f;
    return (uint16_t)((v.u + 0x7fffu + ((v.u>>16)&1u)) >> 16);   // RNE
}
__device__ __forceinline__ float bf2f(uint16_t h){
    union{uint32_t u;float f;} v; v.u=(uint32_t)h<<16; return v.f;
}

// Shared B-buffer k-slots (K=128, stride 136 to break bank conflicts):
//   0..50 = h1, 51 = x, 52..102 = h2, 103..127 = 0.
// L1 A-weights are zero for k>51, L2 A-weights zero at k=51 and k>102, so
// cross-phase slot reuse is harmless (zero weight annihilates stale data).
__global__ __launch_bounds__(BLK, 4)
void lstm_mfma_kernel(const float* __restrict__ inp,    // [B, Tin]
                      const float* __restrict__ Wih1,   // [204, 1]
                      const float* __restrict__ Whh1,   // [204, 51]
                      const float* __restrict__ bih1,   // [204]
                      const float* __restrict__ bhh1,   // [204]
                      const float* __restrict__ Wih2,   // [204, 51]
                      const float* __restrict__ Whh2,   // [204, 51]
                      const float* __restrict__ bih2,   // [204]
                      const float* __restrict__ bhh2,   // [204]
                      const float* __restrict__ Wl,     // [1, 51]
                      const float* __restrict__ blp,    // [1]
                      float* __restrict__ outp)         // [B, Ttot]
{
    const int tid  = threadIdx.x;
    const int wv   = tid >> 6;          // wave = M-tile index (0..12)
    const int ln   = tid & 63;
    const int quad = ln >> 4;
    const int nn   = ln & 15;           // A-row-low16 / B-col / C-col
    const int m0   = wv * 16;
    const int un   = tid >> 4;          // state-thread unit (tid < 816)
    const int bn   = tid & 15;          // state-thread batch
    const int b0   = blockIdx.x * NBB;

    __shared__ __align__(16) uint16_t Bhi[16*136];
    __shared__ __align__(16) uint16_t Blo[16*136];
    __shared__ float gbuf[208*17];      // activated gates [row][batch], +1 pad
    __shared__ float h2f [16*52];       // fp32 h2 [batch][unit] for output dot
    __shared__ float wlb [52];

    for (int k = tid; k < 16*136; k += BLK) { Bhi[k] = 0; Blo[k] = 0; }
    if (tid < Hh) wlb[tid] = Wl[tid];
    if (tid < NBB) {                    // x_0 into the k=51 slot
        float xv = inp[(size_t)(b0+tid)*Tin];
        uint16_t xh = f2bf(xv);
        Bhi[tid*136+51] = xh; Blo[tid*136+51] = f2bf(xv - bf2f(xh));
    }

    // ---- A fragments: weights split bf16 hi/lo (3-product fp32 emulation) --
    short8 a1hi[2], a1lo[2], a2hi[4], a2lo[4];
    const int mr = m0 + nn;             // this lane's A row
#pragma unroll
    for (int s = 0; s < 2; ++s)
#pragma unroll
        for (int j = 0; j < 8; ++j) {
            int k = 32*s + quad*8 + j;
            float w = 0.f;
            if (mr < 204) {
                if (k < Hh)       w = Whh1[mr*Hh + k];
                else if (k == Hh) w = Wih1[mr];          // x column appended
            }
            uint16_t hh = f2bf(w);
            a1hi[s][j] = (short)hh;
            a1lo[s][j] = (short)f2bf(w - bf2f(hh));
        }
#pragma unroll
    for (int s = 0; s < 4; ++s)
#pragma unroll
        for (int j = 0; j < 8; ++j) {
            int k = 32*s + quad*8 + j;
            float w = 0.f;
            if (mr < 204) {
                if (k < Hh)                      w = Wih2[mr*Hh + k];
                else if (k >= 52 && k < 52+Hh)   w = Whh2[mr*Hh + (k-52)];
            }
            uint16_t hh = f2bf(w);
            a2hi[s][j] = (short)hh;
            a2lo[s][j] = (short)f2bf(w - bf2f(hh));
        }

    f32x4 bias1, bias2;
#pragma unroll
    for (int i = 0; i < 4; ++i) {
        int r = m0 + quad*4 + i;        // C row of acc reg i
        bias1[i] = (r < 204) ? (bih1[r] + bhh1[r]) : 0.f;
        bias2[i] = (r < 204) ? (bih2[r] + bhh2[r]) : 0.f;
    }
    const float blv = blp[0];
    float c1 = 0.f, c2 = 0.f;

    __syncthreads();

    for (int t = 0; t < Ttot; ++t) {
        // ---------- Phase A: L1 GEMM (K slabs 0,1 over [h1|x]) ----------
        {
            const uint16_t* bh = &Bhi[nn*136 + quad*8];
            const uint16_t* bl = &Blo[nn*136 + quad*8];
            short8 bh0 = *(const short8*)(bh);
            short8 bl0 = *(const short8*)(bl);
            short8 bh1 = *(const short8*)(bh + 32);
            short8 bl1 = *(const short8*)(bl + 32);
            f32x4 acc0 = bias1, acc1 = {0.f,0.f,0.f,0.f};
            acc0 = __builtin_amdgcn_mfma_f32_16x16x32_bf16(a1hi[0], bh0, acc0, 0,0,0);
            acc1 = __builtin_amdgcn_mfma_f32_16x16x32_bf16(a1hi[1], bh1, acc1, 0,0,0);
            acc0 = __builtin_amdgcn_mfma_f32_16x16x32_bf16(a1lo[0], bh0, acc0, 0,0,0);
            acc1 = __builtin_amdgcn_mfma_f32_16x16x32_bf16(a1lo[1], bh1, acc1, 0,0,0);
            acc0 = __builtin_amdgcn_mfma_f32_16x16x32_bf16(a1hi[0], bl0, acc0, 0,0,0);
            acc1 = __builtin_amdgcn_mfma_f32_16x16x32_bf16(a1hi[1], bl1, acc1, 0,0,0);
#pragma unroll
            for (int i = 0; i < 4; ++i) {
                int r = m0 + quad*4 + i;
                float v = acc0[i] + acc1[i];
                bool tg = (r >= 102) && (r < 153);       // g-gate rows: tanh
                float msc = tg ? 2.f : 1.f, off = tg ? -1.f : 0.f;
                gbuf[r*17 + nn] = __builtin_fmaf(fast_sigmoid(v*msc), msc, off);
            }
        }
        __syncthreads();                                 // bar1
        // ---------- Phase B: L1 state + x prefetch ----------
        if (tid < 816) {
            float gi = gbuf[  un      *17 + bn];
            float gf = gbuf[( Hh+un)  *17 + bn];
            float gg = gbuf[(102+un)  *17 + bn];
            float go = gbuf[(153+un)  *17 + bn];
            c1 = __builtin_fmaf(gf, c1, gi*gg);
            float h1 = go * (2.f*fast_sigmoid(2.f*c1) - 1.f);
            uint16_t hh = f2bf(h1);
            Bhi[bn*136 + un] = hh;
            Blo[bn*136 + un] = f2bf(h1 - bf2f(hh));
        }
        if (wv == 1 && ln < NBB && (t+1) < Tin) {        // x_{t+1} (safe: k51 read in A)
            float xv = inp[(size_t)(b0+ln)*Tin + (t+1)];
            uint16_t xh = f2bf(xv);
            Bhi[ln*136 + 51] = xh;
            Blo[ln*136 + 51] = f2bf(xv - bf2f(xh));
        }
        __syncthreads();                                 // bar2
        // ---------- Phase C: L2 GEMM (K slabs 0..3 over [h1|0|h2]) ----------
        {
            const uint16_t* bh = &Bhi[nn*136 + quad*8];
            const uint16_t* bl = &Blo[nn*136 + quad*8];
            f32x4 acc0 = bias2, acc1 = {0.f,0.f,0.f,0.f};
#pragma unroll
            for (int s = 0; s < 4; ++s) {
                short8 bhs = *(const short8*)(bh + 32*s);
                short8 bls = *(const short8*)(bl + 32*s);
                acc0 = __builtin_amdgcn_mfma_f32_16x16x32_bf16(a2hi[s], bhs, acc0, 0,0,0);
                acc1 = __builtin_amdgcn_mfma_f32_16x16x32_bf16(a2lo[s], bhs, acc1, 0,0,0);
                acc0 = __builtin_amdgcn_mfma_f32_16x16x32_bf16(a2hi[s], bls, acc0, 0,0,0);
            }
#pragma unroll
            for (int i = 0; i < 4; ++i) {
                int r = m0 + quad*4 + i;
                float v = acc0[i] + acc1[i];
                bool tg = (r >= 102) && (r < 153);
                float msc = tg ? 2.f : 1.f, off = tg ? -1.f : 0.f;
                gbuf[r*17 + nn] = __builtin_fmaf(fast_sigmoid(v*msc), msc, off);
            }
        }
        __syncthreads();                                 // bar3
        // ---------- Phase D: L2 state ----------
        if (tid < 816) {
            float gi = gbuf[  un      *17 + bn];
            float gf = gbuf[( Hh+un)  *17 + bn];
            float gg = gbuf[(102+un)  *17 + bn];
            float go = gbuf[(153+un)  *17 + bn];
            c2 = __builtin_fmaf(gf, c2, gi*gg);
            float h2 = go * (2.f*fast_sigmoid(2.f*c2) - 1.f);
            uint16_t hh = f2bf(h2);
            Bhi[bn*136 + 52 + un] = hh;
            Blo[bn*136 + 52 + un] = f2bf(h2 - bf2f(hh));
            h2f[bn*52 + un] = h2;                        // fp32 for output dot
        }
        __syncthreads();                                 // bar4
        // ---------- Phase E: output dot (wave 0; overlaps others' next A) ---
        if (wv == 0) {
            float sacc = 0.f;
#pragma unroll
            for (int ii = 0; ii < 13; ++ii) {
                int u = quad*13 + ii;
                if (u < Hh) sacc = __builtin_fmaf(wlb[u], h2f[nn*52 + u], sacc);
            }
            sacc += __shfl_xor(sacc, 16, 64);
            sacc += __shfl_xor(sacc, 32, 64);
            if (ln < NBB) {
                float ov = sacc + blv;
                outp[(size_t)(b0+ln)*Ttot + t] = ov;
                if (t >= Tin-1) {                        // future feedback -> x slot
                    uint16_t xh = f2bf(ov);
                    Bhi[ln*136 + 51] = xh;
                    Blo[ln*136 + 51] = f2bf(ov - bf2f(xh));
                }
            }
        }
        if (t >= Tin-1) __syncthreads();                 // bar5 (future phase only)
    }
}

extern "C" void kernel_launch(void* const* d_in, const int* in_sizes, int n_in,
                              void* d_out, int out_size, void* d_ws, size_t ws_size,
                              hipStream_t stream) {
    (void)in_sizes; (void)n_in; (void)out_size; (void)d_ws; (void)ws_size;
    lstm_mfma_kernel<<<dim3(Bsz / NBB), dim3(BLK), 0, stream>>>(
        (const float*)d_in[0], (const float*)d_in[1],
        (const float*)d_in[2], (const float*)d_in[3],
        (const float*)d_in[4], (const float*)d_in[5],
        (const float*)d_in[6], (const float*)d_in[7],
        (const float*)d_in[8], (const float*)d_in[9],
        (const float*)d_in[10], (float*)d_out);
}

// Round 9
// 1293.613 us; speedup vs baseline: 1.2712x; 1.0737x over previous
//
#include <hip/hip_runtime.h>
#include <stdint.h>

#define Hh   51
#define Bsz  1024
#define Tin  512
#define Ttot 576      // Tin + future(64)
#define NBB  16       // batches per block (MFMA N)
#define BLK  832      // 13 waves; logical M = 208 rows = 13 tiles of 16
#define BST  144      // per-batch k-stride (uint16) in B buffers

typedef __attribute__((ext_vector_type(8))) short short8;   // 8 x bf16 frag
typedef __attribute__((ext_vector_type(4))) float f32x4;    // C/D frag

__device__ __forceinline__ float fsig(float x){ return 1.f/(1.f+__expf(-x)); }
__device__ __forceinline__ float ftanh(float x){ return 2.f*fsig(2.f*x)-1.f; }
__device__ __forceinline__ uint16_t f2bf(float f){
    union{float f;uint32_t u;} v; v.f=f;
    return (uint16_t)((v.u + 0x7fffu + ((v.u>>16)&1u)) >> 16);   // RNE
}
__device__ __forceinline__ float bf2f(uint16_t h){
    union{uint32_t u;float f;} v; v.u=(uint32_t)h<<16; return v.f;
}

// Logical gate-row m = 4*unit + gate ("unit-major interleave"): the MFMA C
// layout (row = quad*4 + reg) then gives each lane ALL FOUR gate pre-acts of
// unit u = 4*wv + quad, batch nn, in its 4 acc regs -> the LSTM cell update
// is in-register (no gate LDS round-trip, no cross-wave shuffle).
// B buffers (parity double-buffered): k-slots 0..50 = h1, 64..114 = h2,
// rest 0. k-offsets XOR-swizzled by (nn&3)<<3 to kill b128 bank conflicts.
__global__ __launch_bounds__(BLK)
void lstm_mfma2(const float* __restrict__ inp,    // [B, Tin]
                const float* __restrict__ Wih1,   // [204, 1]
                const float* __restrict__ Whh1,   // [204, 51]
                const float* __restrict__ bih1,   // [204]
                const float* __restrict__ bhh1,   // [204]
                const float* __restrict__ Wih2,   // [204, 51]
                const float* __restrict__ Whh2,   // [204, 51]
                const float* __restrict__ bih2,   // [204]
                const float* __restrict__ bhh2,   // [204]
                const float* __restrict__ Wl,     // [1, 51]
                const float* __restrict__ blp,    // [1]
                float* __restrict__ outp)         // [B, Ttot]
{
    const int tid = threadIdx.x;
    const int wv  = tid >> 6, ln = tid & 63;
    const int quad = ln >> 4, nn = ln & 15;
    const int u   = 4*wv + quad;          // hidden unit this lane owns (0..51)
    const bool uv = (u < Hh);
    const int b0  = blockIdx.x * NBB;
    const int swz = (nn & 3) << 3;        // k-offset xor swizzle

    __shared__ __align__(16) uint16_t Bhi[2][NBB*BST];
    __shared__ __align__(16) uint16_t Blo[2][NBB*BST];
    __shared__ float wsum[13*17];         // per-wave output partials [wv][nn]

    for (int k = tid; k < NBB*BST; k += BLK) {
        Bhi[0][k] = 0; Bhi[1][k] = 0; Blo[0][k] = 0; Blo[1][k] = 0;
    }
    if (tid < 13*17) wsum[tid] = 0.f;

    // ---- A fragments: logical row lr -> unit ua = lr>>2, gate ga = lr&3,
    // physical PyTorch row pr = ga*51 + ua. Weights split bf16 hi/lo
    // (3-product fp32 emulation; R8 showed no added error vs fp32).
    const int lr = wv*16 + nn, ua = lr >> 2, ga = lr & 3;
    const bool av = (ua < Hh);
    const int pr = av ? (ga*Hh + ua) : 0;
    short8 a1hi[2], a1lo[2], a2hi[4], a2lo[4];
#pragma unroll
    for (int s = 0; s < 2; ++s)
#pragma unroll
        for (int j = 0; j < 8; ++j) {
            int k = 32*s + quad*8 + j;
            float w = (av && k < Hh) ? Whh1[pr*Hh + k] : 0.f;
            uint16_t hh = f2bf(w);
            a1hi[s][j] = (short)hh; a1lo[s][j] = (short)f2bf(w - bf2f(hh));
        }
#pragma unroll
    for (int s = 0; s < 4; ++s)
#pragma unroll
        for (int j = 0; j < 8; ++j) {
            int k = 32*s + quad*8 + j;
            float w = 0.f;
            if (av) {
                if (k < Hh)                    w = Wih2[pr*Hh + k];
                else if (k >= 64 && k < 64+Hh) w = Whh2[pr*Hh + (k-64)];
            }
            uint16_t hh = f2bf(w);
            a2hi[s][j] = (short)hh; a2lo[s][j] = (short)f2bf(w - bf2f(hh));
        }

    f32x4 bias1, bias2, wih1v;            // per acc-reg i: gate i of unit u
#pragma unroll
    for (int i = 0; i < 4; ++i) {
        int pri = uv ? (i*Hh + u) : 0;
        bias1[i] = uv ? (bih1[pri] + bhh1[pri]) : 0.f;
        bias2[i] = uv ? (bih2[pri] + bhh2[pri]) : 0.f;
        wih1v[i] = uv ? Wih1[pri] : 0.f;
    }
    const float wlu = uv ? Wl[u] : 0.f;
    const float blv = blp[0];
    float c1 = 0.f, c2 = 0.f;
    float xreg = inp[(size_t)(b0 + nn)*Tin];   // x for t=0

    __syncthreads();

    for (int t = 0; t < Ttot; ++t) {
        const int p0 = t & 1, p1 = p0 ^ 1;

        // ---- front: previous step's output (wave 12 writes it; everyone
        // needs it as x in the future phase) — reads prev-step wsum ----
        float x = xreg;
        const bool needsum = (t >= Tin) || (wv == 12);
        if (needsum && t > 0) {
            float osum = blv;
#pragma unroll
            for (int w = 0; w < 13; ++w) osum += wsum[w*17 + nn];
            if (wv == 12 && ln < NBB)
                outp[(size_t)(b0 + ln)*Ttot + (t-1)] = osum;
            if (t >= Tin) x = osum;
        }
        float xnext = 0.f;
        if (t + 1 < Tin) xnext = inp[(size_t)(b0 + nn)*Tin + t + 1];

        // ================= L1: GEMM + in-register cell =================
        {
            const uint16_t* rb = &Bhi[p1][nn*BST + ((quad*8) ^ swz)];
            const uint16_t* rl = &Blo[p1][nn*BST + ((quad*8) ^ swz)];
            short8 h0 = *(const short8*)(rb),      h1f = *(const short8*)(rb + 32);
            short8 l0 = *(const short8*)(rl),      l1f = *(const short8*)(rl + 32);
            f32x4 accA, accB = {0.f,0.f,0.f,0.f};
#pragma unroll
            for (int i = 0; i < 4; ++i) accA[i] = __builtin_fmaf(wih1v[i], x, bias1[i]);
            accA = __builtin_amdgcn_mfma_f32_16x16x32_bf16(a1hi[0], h0,  accA, 0,0,0);
            accB = __builtin_amdgcn_mfma_f32_16x16x32_bf16(a1hi[1], h1f, accB, 0,0,0);
            accA = __builtin_amdgcn_mfma_f32_16x16x32_bf16(a1lo[0], h0,  accA, 0,0,0);
            accB = __builtin_amdgcn_mfma_f32_16x16x32_bf16(a1lo[1], h1f, accB, 0,0,0);
            accA = __builtin_amdgcn_mfma_f32_16x16x32_bf16(a1hi[0], l0,  accA, 0,0,0);
            accB = __builtin_amdgcn_mfma_f32_16x16x32_bf16(a1hi[1], l1f, accB, 0,0,0);
            float vi = accA[0]+accB[0], vf = accA[1]+accB[1];
            float vg = accA[2]+accB[2], vo = accA[3]+accB[3];
            c1 = __builtin_fmaf(fsig(vf), c1, fsig(vi)*ftanh(vg));
            float h1n = fsig(vo) * ftanh(c1);
            if (uv) {
                uint16_t hh = f2bf(h1n);
                int ad = nn*BST + (u & ~31) + ((u & 31) ^ swz);
                Bhi[p0][ad] = hh; Blo[p0][ad] = f2bf(h1n - bf2f(hh));
            }
        }
        __syncthreads();                                   // bar 1

        // ============ L2: GEMM over [h1_t | 0 | h2_{t-1}] + cell ============
        {
            const uint16_t* rb0 = &Bhi[p0][nn*BST + ((quad*8) ^ swz)];  // h1_t
            const uint16_t* rl0 = &Blo[p0][nn*BST + ((quad*8) ^ swz)];
            const uint16_t* rb1 = &Bhi[p1][nn*BST + ((quad*8) ^ swz)];  // h2_{t-1}
            const uint16_t* rl1 = &Blo[p1][nn*BST + ((quad*8) ^ swz)];
            short8 s0h = *(const short8*)(rb0),      s1h = *(const short8*)(rb0 + 32);
            short8 s0l = *(const short8*)(rl0),      s1l = *(const short8*)(rl0 + 32);
            short8 s2h = *(const short8*)(rb1 + 64), s3h = *(const short8*)(rb1 + 96);
            short8 s2l = *(const short8*)(rl1 + 64), s3l = *(const short8*)(rl1 + 96);
            f32x4 accA = bias2, accB = {0.f,0.f,0.f,0.f};
            accA = __builtin_amdgcn_mfma_f32_16x16x32_bf16(a2hi[0], s0h, accA, 0,0,0);
            accB = __builtin_amdgcn_mfma_f32_16x16x32_bf16(a2hi[1], s1h, accB, 0,0,0);
            accA = __builtin_amdgcn_mfma_f32_16x16x32_bf16(a2lo[0], s0h, accA, 0,0,0);
            accB = __builtin_amdgcn_mfma_f32_16x16x32_bf16(a2lo[1], s1h, accB, 0,0,0);
            accA = __builtin_amdgcn_mfma_f32_16x16x32_bf16(a2hi[0], s0l, accA, 0,0,0);
            accB = __builtin_amdgcn_mfma_f32_16x16x32_bf16(a2hi[1], s1l, accB, 0,0,0);
            accA = __builtin_amdgcn_mfma_f32_16x16x32_bf16(a2hi[2], s2h, accA, 0,0,0);
            accB = __builtin_amdgcn_mfma_f32_16x16x32_bf16(a2hi[3], s3h, accB, 0,0,0);
            accA = __builtin_amdgcn_mfma_f32_16x16x32_bf16(a2lo[2], s2h, accA, 0,0,0);
            accB = __builtin_amdgcn_mfma_f32_16x16x32_bf16(a2lo[3], s3h, accB, 0,0,0);
            accA = __builtin_amdgcn_mfma_f32_16x16x32_bf16(a2hi[2], s2l, accA, 0,0,0);
            accB = __builtin_amdgcn_mfma_f32_16x16x32_bf16(a2hi[3], s3l, accB, 0,0,0);
            float vi = accA[0]+accB[0], vf = accA[1]+accB[1];
            float vg = accA[2]+accB[2], vo = accA[3]+accB[3];
            c2 = __builtin_fmaf(fsig(vf), c2, fsig(vi)*ftanh(vg));
            float h2n = fsig(vo) * ftanh(c2);
            if (uv) {
                uint16_t hh = f2bf(h2n);
                int sl = 64 + u;
                int ad = nn*BST + (sl & ~31) + ((sl & 31) ^ swz);
                Bhi[p0][ad] = hh; Blo[p0][ad] = f2bf(h2n - bf2f(hh));
            }
            // output partials: sum wl[u]*h2 over this wave's 4 units
            float part = wlu * h2n;
            part += __shfl_xor(part, 16, 64);
            part += __shfl_xor(part, 32, 64);
            if (quad == 0) wsum[wv*17 + nn] = part;
        }
        __syncthreads();                                   // bar 2
        xreg = xnext;
    }

    // final output (t = Ttot-1)
    if (wv == 12) {
        float osum = blv;
#pragma unroll
        for (int w = 0; w < 13; ++w) osum += wsum[w*17 + nn];
        if (ln < NBB) outp[(size_t)(b0 + ln)*Ttot + (Ttot-1)] = osum;
    }
}

extern "C" void kernel_launch(void* const* d_in, const int* in_sizes, int n_in,
                              void* d_out, int out_size, void* d_ws, size_t ws_size,
                              hipStream_t stream) {
    (void)in_sizes; (void)n_in; (void)out_size; (void)d_ws; (void)ws_size;
    lstm_mfma2<<<dim3(Bsz / NBB), dim3(BLK), 0, stream>>>(
        (const float*)d_in[0], (const float*)d_in[1],
        (const float*)d_in[2], (const float*)d_in[3],
        (const float*)d_in[4], (const float*)d_in[5],
        (const float*)d_in[6], (const float*)d_in[7],
        (const float*)d_in[8], (const float*)d_in[9],
        (const float*)d_in[10], (float*)d_out);
}

// Round 10
// 1276.765 us; speedup vs baseline: 1.2880x; 1.0132x over previous
//
#include <hip/hip_runtime.h>
#include <stdint.h>

#define Hh   51
#define Bsz  1024
#define Tin  512
#define Ttot 576      // Tin + future(64)
#define NBB  16       // batches per block (MFMA N)
#define NW   7        // waves per block; each wave owns 2 M-tiles (14 >= 13)
#define BLK  (NW*64)  // 448
#define BST  136      // per-batch k-stride (uint16) = 68 dwords: 68*4 mod 32 = 16
                      // -> no 4-way bank alias across nn (R9's 72-dword stride had it)

typedef __attribute__((ext_vector_type(8))) short short8;   // 8 x bf16 frag
typedef __attribute__((ext_vector_type(4))) float f32x4;    // C/D frag

__device__ __forceinline__ float fsig(float x){ return 1.f/(1.f+__expf(-x)); }
__device__ __forceinline__ float ftanh(float x){ return 2.f*fsig(2.f*x)-1.f; }
__device__ __forceinline__ uint16_t f2bf(float f){
    union{float f;uint32_t u;} v; v.f=f;
    return (uint16_t)((v.u + 0x7fffu + ((v.u>>16)&1u)) >> 16);   // RNE
}
__device__ __forceinline__ float bf2f(uint16_t h){
    union{uint32_t u;float f;} v; v.u=(uint32_t)h<<16; return v.f;
}
#define MFMA __builtin_amdgcn_mfma_f32_16x16x32_bf16

// Logical gate-row m = 4*unit + gate: MFMA C layout (row=quad*4+reg) gives one
// lane all 4 gate pre-acts of unit 4*(wv+7*tl)+quad, batch nn -> in-register
// cell. Each wave computes TWO M-tiles (wv, wv+7) from ONE set of B fragments:
// halves the block's LDS read traffic vs R9 (the measured bottleneck).
// B buffers parity-double-buffered; k-slots 0..50 = h1, 64..114 = h2, rest 0.
__global__ __launch_bounds__(BLK, 2)
void lstm_mfma3(const float* __restrict__ inp,    // [B, Tin]
                const float* __restrict__ Wih1,   // [204, 1]
                const float* __restrict__ Whh1,   // [204, 51]
                const float* __restrict__ bih1,   // [204]
                const float* __restrict__ bhh1,   // [204]
                const float* __restrict__ Wih2,   // [204, 51]
                const float* __restrict__ Whh2,   // [204, 51]
                const float* __restrict__ bih2,   // [204]
                const float* __restrict__ bhh2,   // [204]
                const float* __restrict__ Wl,     // [1, 51]
                const float* __restrict__ blp,    // [1]
                float* __restrict__ outp)         // [B, Ttot]
{
    const int tid = threadIdx.x;
    const int wv  = tid >> 6, ln = tid & 63;
    const int quad = ln >> 4, nn = ln & 15;
    const int b0  = blockIdx.x * NBB;

    __shared__ __align__(16) uint16_t Bhi[2][NBB*BST];
    __shared__ __align__(16) uint16_t Blo[2][NBB*BST];
    __shared__ float wsum[NW*17];         // per-wave output partials [wv][nn]

    for (int k = tid; k < NBB*BST; k += BLK) {
        Bhi[0][k] = 0; Bhi[1][k] = 0; Blo[0][k] = 0; Blo[1][k] = 0;
    }
    if (tid < NW*17) wsum[tid] = 0.f;

    // ---- A fragments for 2 tiles, weights split bf16 hi/lo (3-product) ----
    short8 a1hi[2][2], a1lo[2][2], a2hi[2][4], a2lo[2][4];
    f32x4 bias1[2], bias2[2], wih1v[2];
    float wlu[2]; int ut[2]; bool uvt[2];
#pragma unroll
    for (int tl = 0; tl < 2; ++tl) {
        const int rbase = 16*(wv + 7*tl);         // logical row base of tile
        const int lr = rbase + nn;                // this lane's A row
        const int ua = lr >> 2, ga = lr & 3;      // unit / gate of that row
        const bool av = (ua < Hh);
        const int pr = av ? (ga*Hh + ua) : 0;     // physical PyTorch row
#pragma unroll
        for (int s = 0; s < 2; ++s)
#pragma unroll
            for (int j = 0; j < 8; ++j) {
                int k = 32*s + quad*8 + j;
                float w = (av && k < Hh) ? Whh1[pr*Hh + k] : 0.f;
                uint16_t hh = f2bf(w);
                a1hi[tl][s][j] = (short)hh;
                a1lo[tl][s][j] = (short)f2bf(w - bf2f(hh));
            }
#pragma unroll
        for (int s = 0; s < 4; ++s)
#pragma unroll
            for (int j = 0; j < 8; ++j) {
                int k = 32*s + quad*8 + j;
                float w = 0.f;
                if (av) {
                    if (k < Hh)                    w = Wih2[pr*Hh + k];
                    else if (k >= 64 && k < 64+Hh) w = Whh2[pr*Hh + (k-64)];
                }
                uint16_t hh = f2bf(w);
                a2hi[tl][s][j] = (short)hh;
                a2lo[tl][s][j] = (short)f2bf(w - bf2f(hh));
            }
        const int u = 4*(wv + 7*tl) + quad;       // unit this lane's cell owns
        ut[tl] = u; uvt[tl] = (u < Hh);
#pragma unroll
        for (int i = 0; i < 4; ++i) {
            int pri = uvt[tl] ? (i*Hh + u) : 0;
            bias1[tl][i] = uvt[tl] ? (bih1[pri] + bhh1[pri]) : 0.f;
            bias2[tl][i] = uvt[tl] ? (bih2[pri] + bhh2[pri]) : 0.f;
            wih1v[tl][i] = uvt[tl] ? Wih1[pri] : 0.f;
        }
        wlu[tl] = uvt[tl] ? Wl[u] : 0.f;
    }
    const float blv = blp[0];
    float c1[2] = {0.f, 0.f}, c2[2] = {0.f, 0.f};
    float xreg = inp[(size_t)(b0 + nn)*Tin];      // x for t=0

    __syncthreads();

    for (int t = 0; t < Ttot; ++t) {
        const int p0 = t & 1, p1 = p0 ^ 1;

        // ---- front: previous step's output (wave NW-1 stores; all waves
        // need it as x in the future phase) ----
        float x = xreg;
        if ((t >= Tin || wv == NW-1) && t > 0) {
            float osum = blv;
#pragma unroll
            for (int w = 0; w < NW; ++w) osum += wsum[w*17 + nn];
            if (wv == NW-1 && ln < NBB)
                outp[(size_t)(b0 + ln)*Ttot + (t-1)] = osum;
            if (t >= Tin) x = osum;
        }
        float xnext = 0.f;
        if (t + 1 < Tin) xnext = inp[(size_t)(b0 + nn)*Tin + t + 1];

        // ================= L1: GEMM + in-register cells =================
        {
            const uint16_t* rb = &Bhi[p1][nn*BST + quad*8];
            const uint16_t* rl = &Blo[p1][nn*BST + quad*8];
            short8 h0 = *(const short8*)(rb),      h1f = *(const short8*)(rb + 32);
            short8 l0 = *(const short8*)(rl),      l1f = *(const short8*)(rl + 32);
            f32x4 aA[2], aB[2];
#pragma unroll
            for (int tl = 0; tl < 2; ++tl) {
#pragma unroll
                for (int i = 0; i < 4; ++i)
                    aA[tl][i] = __builtin_fmaf(wih1v[tl][i], x, bias1[tl][i]);
                aB[tl] = (f32x4){0.f,0.f,0.f,0.f};
            }
            aA[0] = MFMA(a1hi[0][0], h0, aA[0], 0,0,0);
            aB[0] = MFMA(a1hi[0][1], h1f, aB[0], 0,0,0);
            aA[1] = MFMA(a1hi[1][0], h0, aA[1], 0,0,0);
            aB[1] = MFMA(a1hi[1][1], h1f, aB[1], 0,0,0);
            aA[0] = MFMA(a1lo[0][0], h0, aA[0], 0,0,0);
            aB[0] = MFMA(a1lo[0][1], h1f, aB[0], 0,0,0);
            aA[1] = MFMA(a1lo[1][0], h0, aA[1], 0,0,0);
            aB[1] = MFMA(a1lo[1][1], h1f, aB[1], 0,0,0);
            aA[0] = MFMA(a1hi[0][0], l0, aA[0], 0,0,0);
            aB[0] = MFMA(a1hi[0][1], l1f, aB[0], 0,0,0);
            aA[1] = MFMA(a1hi[1][0], l0, aA[1], 0,0,0);
            aB[1] = MFMA(a1hi[1][1], l1f, aB[1], 0,0,0);
#pragma unroll
            for (int tl = 0; tl < 2; ++tl) {
                float vi = aA[tl][0]+aB[tl][0], vf = aA[tl][1]+aB[tl][1];
                float vg = aA[tl][2]+aB[tl][2], vo = aA[tl][3]+aB[tl][3];
                c1[tl] = __builtin_fmaf(fsig(vf), c1[tl], fsig(vi)*ftanh(vg));
                float h1n = fsig(vo) * ftanh(c1[tl]);
                if (uvt[tl]) {
                    uint16_t hh = f2bf(h1n);
                    int ad = nn*BST + ut[tl];
                    Bhi[p0][ad] = hh; Blo[p0][ad] = f2bf(h1n - bf2f(hh));
                }
            }
        }
        __syncthreads();                                   // bar 1

        // ============ L2: GEMM over [h1_t | 0 | h2_{t-1}] + cells ============
        float h2v[2];
        {
            const uint16_t* rb0 = &Bhi[p0][nn*BST + quad*8];   // h1_t
            const uint16_t* rl0 = &Blo[p0][nn*BST + quad*8];
            const uint16_t* rb1 = &Bhi[p1][nn*BST + quad*8];   // h2_{t-1}
            const uint16_t* rl1 = &Blo[p1][nn*BST + quad*8];
            short8 s0h = *(const short8*)(rb0),      s1h = *(const short8*)(rb0 + 32);
            short8 s0l = *(const short8*)(rl0),      s1l = *(const short8*)(rl0 + 32);
            short8 s2h = *(const short8*)(rb1 + 64), s3h = *(const short8*)(rb1 + 96);
            short8 s2l = *(const short8*)(rl1 + 64), s3l = *(const short8*)(rl1 + 96);
            f32x4 aA[2], aB[2];
#pragma unroll
            for (int tl = 0; tl < 2; ++tl) {
                aA[tl] = bias2[tl];
                aB[tl] = (f32x4){0.f,0.f,0.f,0.f};
            }
#pragma unroll
            for (int tl = 0; tl < 2; ++tl) {
                aA[tl] = MFMA(a2hi[tl][0], s0h, aA[tl], 0,0,0);
                aB[tl] = MFMA(a2hi[tl][1], s1h, aB[tl], 0,0,0);
                aA[tl] = MFMA(a2lo[tl][0], s0h, aA[tl], 0,0,0);
                aB[tl] = MFMA(a2lo[tl][1], s1h, aB[tl], 0,0,0);
                aA[tl] = MFMA(a2hi[tl][0], s0l, aA[tl], 0,0,0);
                aB[tl] = MFMA(a2hi[tl][1], s1l, aB[tl], 0,0,0);
                aA[tl] = MFMA(a2hi[tl][2], s2h, aA[tl], 0,0,0);
                aB[tl] = MFMA(a2hi[tl][3], s3h, aB[tl], 0,0,0);
                aA[tl] = MFMA(a2lo[tl][2], s2h, aA[tl], 0,0,0);
                aB[tl] = MFMA(a2lo[tl][3], s3h, aB[tl], 0,0,0);
                aA[tl] = MFMA(a2hi[tl][2], s2l, aA[tl], 0,0,0);
                aB[tl] = MFMA(a2hi[tl][3], s3l, aB[tl], 0,0,0);
            }
#pragma unroll
            for (int tl = 0; tl < 2; ++tl) {
                float vi = aA[tl][0]+aB[tl][0], vf = aA[tl][1]+aB[tl][1];
                float vg = aA[tl][2]+aB[tl][2], vo = aA[tl][3]+aB[tl][3];
                c2[tl] = __builtin_fmaf(fsig(vf), c2[tl], fsig(vi)*ftanh(vg));
                h2v[tl] = fsig(vo) * ftanh(c2[tl]);
                if (uvt[tl]) {
                    uint16_t hh = f2bf(h2v[tl]);
                    int ad = nn*BST + 64 + ut[tl];
                    Bhi[p0][ad] = hh; Blo[p0][ad] = f2bf(h2v[tl] - bf2f(hh));
                }
            }
            // output partials over this wave's 8 units (2 tiles x 4 quads)
            float part = __builtin_fmaf(wlu[0], h2v[0], wlu[1]*h2v[1]);
            part += __shfl_xor(part, 16, 64);
            part += __shfl_xor(part, 32, 64);
            if (quad == 0) wsum[wv*17 + nn] = part;
        }
        __syncthreads();                                   // bar 2
        xreg = xnext;
    }

    // final output (t = Ttot-1)
    if (wv == NW-1) {
        float osum = blv;
#pragma unroll
        for (int w = 0; w < NW; ++w) osum += wsum[w*17 + nn];
        if (ln < NBB) outp[(size_t)(b0 + ln)*Ttot + (Ttot-1)] = osum;
    }
}

extern "C" void kernel_launch(void* const* d_in, const int* in_sizes, int n_in,
                              void* d_out, int out_size, void* d_ws, size_t ws_size,
                              hipStream_t stream) {
    (void)in_sizes; (void)n_in; (void)out_size; (void)d_ws; (void)ws_size;
    lstm_mfma3<<<dim3(Bsz / NBB), dim3(BLK), 0, stream>>>(
        (const float*)d_in[0], (const float*)d_in[1],
        (const float*)d_in[2], (const float*)d_in[3],
        (const float*)d_in[4], (const float*)d_in[5],
        (const float*)d_in[6], (const float*)d_in[7],
        (const float*)d_in[8], (const float*)d_in[9],
        (const float*)d_in[10], (float*)d_out);
}